// Round 3
// baseline (672.187 us; speedup 1.0000x reference)
//
#include <hip/hip_runtime.h>

// FractalDimension: out[row] = sum_{l=0}^{1023} in[row*1024 + l] / (l+1)
// rows = C*B*N = 131072, L = 1024, fp32 in/out.
// HBM floor: 512 MB read @ ~6.3 TB/s -> ~85 us kernel time.
//
// R2 design: one wave per 16 consecutive rows (64 KB), 16 register
// accumulators, per-lane precomputed reciprocals (FMA, no fp32 div).
// The 6-step butterfly reduce runs as 16 independent pipelined chains
// once per 64 KB (vs once per 4 KB in R1). Coalesced 64 B final store.

constexpr int kL = 1024;
constexpr int kThreads = 256;
constexpr int kRowsPerWave = 16;

typedef float f4 __attribute__((ext_vector_type(4)));

__global__ __launch_bounds__(kThreads) void FractalDimension_kernel(
    const float* __restrict__ in, float* __restrict__ out, int rows) {
  const int lane = threadIdx.x & 63;
  const int wave = blockIdx.x * (kThreads >> 6) + (threadIdx.x >> 6);
  const int rowBase = wave * kRowsPerWave;
  if (rowBase >= rows) return;

  // Lane's element positions within a row: (k*64 + lane)*4 + c, k=0..3, c=0..3.
  float r[4][4];
#pragma unroll
  for (int k = 0; k < 4; ++k)
#pragma unroll
    for (int c = 0; c < 4; ++c)
      r[k][c] = 1.0f / (float)((k * 64 + lane) * 4 + c + 1);

  const f4* p = reinterpret_cast<const f4*>(in + (size_t)rowBase * kL);
  // p[j*256 + k*64 + lane] = row (rowBase+j), elements (k*64+lane)*4 .. +3

  float acc[kRowsPerWave];
#pragma unroll
  for (int j = 0; j < kRowsPerWave; ++j) acc[j] = 0.0f;

#pragma unroll
  for (int k = 0; k < 4; ++k) {
#pragma unroll
    for (int jj = 0; jj < kRowsPerWave; jj += 8) {
      f4 v[8];
#pragma unroll
      for (int j = 0; j < 8; ++j)
        v[j] = p[(size_t)(jj + j) * 256 + k * 64 + lane];
#pragma unroll
      for (int j = 0; j < 8; ++j)
        acc[jj + j] += v[j].x * r[k][0] + v[j].y * r[k][1] +
                       v[j].z * r[k][2] + v[j].w * r[k][3];
    }
  }

  // 16 independent butterfly chains, pipelined: step outer, row inner.
#pragma unroll
  for (int off = 32; off > 0; off >>= 1) {
#pragma unroll
    for (int j = 0; j < kRowsPerWave; ++j)
      acc[j] += __shfl_xor(acc[j], off, 64);
  }

  // Every lane now holds all 16 totals; lane j stores row rowBase+j.
  float res = acc[0];
#pragma unroll
  for (int j = 1; j < kRowsPerWave; ++j)
    res = (lane == j) ? acc[j] : res;
  if (lane < kRowsPerWave) out[rowBase + lane] = res;
}

extern "C" void kernel_launch(void* const* d_in, const int* in_sizes, int n_in,
                              void* d_out, int out_size, void* d_ws, size_t ws_size,
                              hipStream_t stream) {
  const float* in = (const float*)d_in[0];
  float* out = (float*)d_out;
  const int rows = in_sizes[0] / kL;  // 131072
  const int wavesNeeded = (rows + kRowsPerWave - 1) / kRowsPerWave;  // 8192
  const int blocks = (wavesNeeded + (kThreads >> 6) - 1) / (kThreads >> 6);  // 2048
  FractalDimension_kernel<<<blocks, kThreads, 0, stream>>>(in, out, rows);
}